// Round 2
// baseline (3936.519 us; speedup 1.0000x reference)
//
#include <hip/hip_runtime.h>
#include <math.h>

#define N0c 500000
#define Rc  100000
#define NDc 50000
#define E0c 2000000
#define E1c 1000000

// order-preserving float<->uint mapping for atomicMax on floats
static __device__ __forceinline__ unsigned f2u(float f) {
    unsigned u = __float_as_uint(f);
    return (u & 0x80000000u) ? ~u : (u | 0x80000000u);
}
static __device__ __forceinline__ float u2f(unsigned u) {
    unsigned v = (u & 0x80000000u) ? (u & 0x7fffffffu) : ~u;
    return __uint_as_float(v);
}

// ---- count nodes per review graph (cnt = segment_sum(ones, node_graph)) ----
__global__ void k_count(const int* __restrict__ node_graph, unsigned* __restrict__ cnt, int n) {
    int i = blockIdx.x * blockDim.x + threadIdx.x;
    if (i < n) atomicAdd(&cnt[node_graph[i]], 1u);
}

// ---- fused hypergraph scatter + graph pool: r_acc[g] += x[src]*coef ----
// 16 lanes per edge, float4 per lane (64 floats per row)
__global__ void k_scatter0(const float* __restrict__ x, const float* __restrict__ norm_n,
                           const float* __restrict__ norm_e, const int* __restrict__ src0,
                           const int* __restrict__ dst0, const int* __restrict__ node_graph,
                           float* __restrict__ r_acc, int E0) {
    int t = blockIdx.x * blockDim.x + threadIdx.x;
    int e = t >> 4, lane = t & 15;
    if (e >= E0) return;
    int s = src0[e], d = dst0[e];
    float coef = norm_n[s] * norm_n[d] * norm_e[e];
    int g = node_graph[d];
    float4 v = ((const float4*)(x + (size_t)s * 64))[lane];
    float* p = r_acc + (size_t)g * 64 + lane * 4;
    atomicAdd(p + 0, v.x * coef);
    atomicAdd(p + 1, v.y * coef);
    atomicAdd(p + 2, v.z * coef);
    atomicAdd(p + 3, v.w * coef);
}

// ---- fused MLP: r = leaky(mean @ W1 + b1); feat = r @ Wsrc + bsrc;
//      score_src[r,h] = sum_d leaky(feat,0.2)*attn[h,d]  (GATv2 src-only score) ----
__global__ __launch_bounds__(256) void k_mlp(const float* __restrict__ r_acc,
                                             const unsigned* __restrict__ cnt,
                                             const float* __restrict__ W1,
                                             const float* __restrict__ b1,
                                             const float* __restrict__ Wsrc,
                                             const float* __restrict__ bsrc,
                                             const float* __restrict__ attn,
                                             float* __restrict__ feat,
                                             float* __restrict__ score_src, int R) {
    __shared__ float W1s[64 * 64];
    __shared__ float Wss[64 * 128];
    __shared__ float b1s[64], bss[128], atts[128];
    __shared__ float vbuf[2][64], t1buf[2][64];
    int tid = threadIdx.x;
    for (int i = tid; i < 4096; i += 256) W1s[i] = W1[i];
    for (int i = tid; i < 8192; i += 256) Wss[i] = Wsrc[i];
    if (tid < 64) b1s[tid] = b1[tid];
    if (tid < 128) bss[tid] = bsrc[tid];
    if (tid < 128) atts[tid] = attn[tid];
    __syncthreads();

    int slot = tid >> 7, j = tid & 127;  // 2 rows per block, 128 threads per row
    for (int row0 = blockIdx.x * 2; row0 < R; row0 += gridDim.x * 2) {
        int row = row0 + slot;
        bool active = row < R;
        if (active && j < 64)
            vbuf[slot][j] = r_acc[(size_t)row * 64 + j] / (float)cnt[row];
        __syncthreads();
        if (active && j < 64) {
            float acc = 0.f;
#pragma unroll
            for (int k = 0; k < 64; k++) acc += vbuf[slot][k] * W1s[k * 64 + j];
            acc += b1s[j];
            t1buf[slot][j] = acc >= 0.f ? acc : 0.01f * acc;
        }
        __syncthreads();
        if (active) {
            float acc = 0.f;
#pragma unroll
            for (int k = 0; k < 64; k++) acc += t1buf[slot][k] * Wss[k * 128 + j];
            acc += bss[j];
            feat[(size_t)row * 128 + j] = acc;
            float lk = acc >= 0.f ? acc : 0.2f * acc;
            float p = lk * atts[j];
            // reduce over the 32 lanes of each head (j%32), within 64-lane wave
#pragma unroll
            for (int m = 16; m >= 1; m >>= 1) p += __shfl_xor(p, m, 32);
            if ((j & 31) == 0) score_src[(size_t)row * 4 + (j >> 5)] = p;
        }
        __syncthreads();
    }
}

// ---- per-destination segment max of scores ----
__global__ void k_smax(const float* __restrict__ score_src, const int* __restrict__ src1,
                       const int* __restrict__ dst1, unsigned* __restrict__ smax, int E1) {
    int e = blockIdx.x * blockDim.x + threadIdx.x;
    if (e >= E1) return;
    int s = src1[e], d = dst1[e];
    float4 sc = ((const float4*)score_src)[s];
    atomicMax(&smax[d * 4 + 0], f2u(sc.x));
    atomicMax(&smax[d * 4 + 1], f2u(sc.y));
    atomicMax(&smax[d * 4 + 2], f2u(sc.z));
    atomicMax(&smax[d * 4 + 3], f2u(sc.w));
}

// ---- weighted scatter: ftn[dst] += exp(score-max)*feat[src]; ssum[dst,h] += ex ----
// 32 lanes per edge x float4 = 128 floats (H*FINAL_DIM). head = lane/8.
__global__ void k_scatter1(const float* __restrict__ feat, const float* __restrict__ score_src,
                           const int* __restrict__ src1, const int* __restrict__ dst1,
                           const unsigned* __restrict__ smax, float* __restrict__ ssum,
                           float* __restrict__ ftn, int E1) {
    int t = blockIdx.x * blockDim.x + threadIdx.x;
    int e = t >> 5, lane = t & 31;
    if (e >= E1) return;
    int s = src1[e], d = dst1[e];
    int h = lane >> 3;  // lane*4 floats -> head = (lane*4)/32, h in [0,4)
    float sc = score_src[(size_t)s * 4 + h];
    float mx = u2f(smax[d * 4 + h]);
    float ex = __expf(sc - mx);
    if ((lane & 7) == 0) atomicAdd(&ssum[d * 4 + h], ex);
    float4 v = ((const float4*)(feat + (size_t)s * 128))[lane];
    float* p = ftn + (size_t)d * 128 + lane * 4;
    atomicAdd(p + 0, v.x * ex);
    atomicAdd(p + 1, v.y * ex);
    atomicAdd(p + 2, v.z * ex);
    atomicAdd(p + 3, v.w * ex);
}

// ---- finalize: out[nd,d] = sum_h ftn[nd,h,d] / ssum[nd,h] ----
__global__ void k_final(const float* __restrict__ ftn, const float* __restrict__ ssum,
                        float* __restrict__ out, int ND) {
    int t = blockIdx.x * blockDim.x + threadIdx.x;
    if (t >= ND * 32) return;
    int nd = t >> 5, dd = t & 31;
    float acc = 0.f;
#pragma unroll
    for (int h = 0; h < 4; h++)
        acc += ftn[(size_t)nd * 128 + h * 32 + dd] / ssum[nd * 4 + h];
    out[t] = acc;
}

extern "C" void kernel_launch(void* const* d_in, const int* in_sizes, int n_in,
                              void* d_out, int out_size, void* d_ws, size_t ws_size,
                              hipStream_t stream) {
    const float* x      = (const float*)d_in[0];
    const float* norm_n = (const float*)d_in[1];
    const float* norm_e = (const float*)d_in[2];
    const float* W1     = (const float*)d_in[3];
    const float* b1     = (const float*)d_in[4];
    const float* Wsrc   = (const float*)d_in[5];
    const float* bsrc   = (const float*)d_in[6];
    const float* attn   = (const float*)d_in[7];
    const int* src0     = (const int*)d_in[8];
    const int* dst0     = (const int*)d_in[9];
    const int* node_graph = (const int*)d_in[10];
    const int* src1     = (const int*)d_in[11];
    const int* dst1     = (const int*)d_in[12];
    float* out = (float*)d_out;

    float* ws = (float*)d_ws;
    size_t off = 0;
    float* r_acc = ws + off;               off += (size_t)Rc * 64;   // 6.4M
    float* ftn   = ws + off;               off += (size_t)NDc * 128; // 6.4M
    float* ssum  = ws + off;               off += (size_t)NDc * 4;
    unsigned* smax = (unsigned*)(ws + off); off += (size_t)NDc * 4;
    unsigned* cnt  = (unsigned*)(ws + off); off += (size_t)Rc;
    size_t zero_elems = off;               // everything above needs zero-init
    float* feat      = ws + off;           off += (size_t)Rc * 128;
    float* score_src = ws + off;           off += (size_t)Rc * 4;

    hipMemsetAsync(d_ws, 0, zero_elems * sizeof(float), stream);

    k_count<<<(N0c + 255) / 256, 256, 0, stream>>>(node_graph, cnt, N0c);
    k_scatter0<<<(E0c * 16 + 255) / 256, 256, 0, stream>>>(
        x, norm_n, norm_e, src0, dst0, node_graph, r_acc, E0c);
    k_mlp<<<2048, 256, 0, stream>>>(r_acc, cnt, W1, b1, Wsrc, bsrc, attn, feat, score_src, Rc);
    k_smax<<<(E1c + 255) / 256, 256, 0, stream>>>(score_src, src1, dst1, smax, E1c);
    k_scatter1<<<((size_t)E1c * 32 + 255) / 256, 256, 0, stream>>>(
        feat, score_src, src1, dst1, smax, ssum, ftn, E1c);
    k_final<<<(NDc * 32 + 255) / 256, 256, 0, stream>>>(ftn, ssum, out, NDc);
}

// Round 3
// 989.423 us; speedup vs baseline: 3.9786x; 3.9786x over previous
//
#include <hip/hip_runtime.h>
#include <math.h>

#define N0c 500000
#define Rc  100000
#define NDc 50000
#define E0c 2000000
#define E1c 1000000

// ---------------- histogram / count kernels ----------------
__global__ void k_count(const int* __restrict__ node_graph, unsigned* __restrict__ cnt, int n) {
    int i = blockIdx.x * blockDim.x + threadIdx.x;
    if (i < n) atomicAdd(&cnt[node_graph[i]], 1u);
}

__global__ void k_hist0(const int* __restrict__ dst0, const int* __restrict__ node_graph,
                        unsigned* __restrict__ cnt0, int E0) {
    int e = blockIdx.x * blockDim.x + threadIdx.x;
    if (e < E0) atomicAdd(&cnt0[node_graph[dst0[e]]], 1u);
}

__global__ void k_hist1(const int* __restrict__ dst1, unsigned* __restrict__ cnt1, int E1) {
    int e = blockIdx.x * blockDim.x + threadIdx.x;
    if (e < E1) atomicAdd(&cnt1[dst1[e]], 1u);
}

// ---------------- 3-pass exclusive scan (n <= 1024*1024) ----------------
__global__ void k_scan1(const unsigned* __restrict__ in, unsigned* __restrict__ out,
                        unsigned* __restrict__ bsum, int n) {
    __shared__ unsigned s[1024];
    int i = blockIdx.x * 1024 + threadIdx.x;
    unsigned v = (i < n) ? in[i] : 0u;
    s[threadIdx.x] = v;
    __syncthreads();
    for (int off = 1; off < 1024; off <<= 1) {
        unsigned t = (threadIdx.x >= off) ? s[threadIdx.x - off] : 0u;
        __syncthreads();
        s[threadIdx.x] += t;
        __syncthreads();
    }
    if (i < n) out[i] = s[threadIdx.x] - v;  // exclusive within block
    if (threadIdx.x == 1023) bsum[blockIdx.x] = s[1023];
}

__global__ void k_scan2(unsigned* __restrict__ bsum, int nb) {
    __shared__ unsigned s[1024];
    unsigned v = (threadIdx.x < nb) ? bsum[threadIdx.x] : 0u;
    s[threadIdx.x] = v;
    __syncthreads();
    for (int off = 1; off < 1024; off <<= 1) {
        unsigned t = (threadIdx.x >= off) ? s[threadIdx.x - off] : 0u;
        __syncthreads();
        s[threadIdx.x] += t;
        __syncthreads();
    }
    if (threadIdx.x < nb) bsum[threadIdx.x] = s[threadIdx.x] - v;  // exclusive
}

__global__ void k_scan3(unsigned* __restrict__ out, const unsigned* __restrict__ bsum,
                        unsigned* __restrict__ cursor, int n) {
    int i = blockIdx.x * 1024 + threadIdx.x;
    if (i < n) {
        unsigned v = out[i] + bsum[blockIdx.x];
        out[i] = v;
        cursor[i] = v;
    }
}

// ---------------- place edge ids into CSR ----------------
__global__ void k_place0(const int* __restrict__ dst0, const int* __restrict__ node_graph,
                         unsigned* __restrict__ cursor, int* __restrict__ eid, int E0) {
    int e = blockIdx.x * blockDim.x + threadIdx.x;
    if (e < E0) {
        int g = node_graph[dst0[e]];
        unsigned p = atomicAdd(&cursor[g], 1u);
        eid[p] = e;
    }
}

__global__ void k_place1(const int* __restrict__ dst1, unsigned* __restrict__ cursor,
                         int* __restrict__ eid, int E1) {
    int e = blockIdx.x * blockDim.x + threadIdx.x;
    if (e < E1) {
        unsigned p = atomicAdd(&cursor[dst1[e]], 1u);
        eid[p] = e;
    }
}

// ---------------- gather-reduce 0: r[g,:] = mean over graph-nodes of h ----------------
// one wave (64 lanes) per review-graph; lane = feature index (64 floats)
__global__ __launch_bounds__(256) void k_gather0(
        const float* __restrict__ x, const float* __restrict__ norm_n,
        const float* __restrict__ norm_e, const int* __restrict__ src0,
        const int* __restrict__ dst0, const int* __restrict__ eid,
        const unsigned* __restrict__ offs, const unsigned* __restrict__ cntN,
        float* __restrict__ r, int R, int E0) {
    int wid = (blockIdx.x * blockDim.x + threadIdx.x) >> 6;
    int lane = threadIdx.x & 63;
    if (wid >= R) return;
    unsigned beg = offs[wid];
    unsigned end = (wid + 1 < R) ? offs[wid + 1] : (unsigned)E0;
    float acc = 0.f;
    for (unsigned base = beg; base < end; base += 64u) {
        int m = (int)min(64u, end - base);
        int s = 0;
        float coef = 0.f;
        if (lane < m) {
            int e = eid[base + lane];
            s = src0[e];
            int d = dst0[e];
            coef = norm_n[s] * norm_n[d] * norm_e[e];
        }
        for (int j = 0; j < m; j++) {
            int sj = __shfl(s, j);
            float cj = __shfl(coef, j);
            acc += x[(size_t)sj * 64 + lane] * cj;
        }
    }
    r[(size_t)wid * 64 + lane] = acc / (float)cntN[wid];
}

// ---------------- fused MLP + GATv2 source score ----------------
__global__ __launch_bounds__(256) void k_mlp(const float* __restrict__ r_in,
                                             const float* __restrict__ W1,
                                             const float* __restrict__ b1,
                                             const float* __restrict__ Wsrc,
                                             const float* __restrict__ bsrc,
                                             const float* __restrict__ attn,
                                             float* __restrict__ feat,
                                             float* __restrict__ score_src, int R) {
    __shared__ float W1s[64 * 64];
    __shared__ float Wss[64 * 128];
    __shared__ float b1s[64], bss[128], atts[128];
    __shared__ float vbuf[2][64], t1buf[2][64];
    int tid = threadIdx.x;
    for (int i = tid; i < 4096; i += 256) W1s[i] = W1[i];
    for (int i = tid; i < 8192; i += 256) Wss[i] = Wsrc[i];
    if (tid < 64) b1s[tid] = b1[tid];
    if (tid < 128) bss[tid] = bsrc[tid];
    if (tid < 128) atts[tid] = attn[tid];
    __syncthreads();

    int slot = tid >> 7, j = tid & 127;  // 2 rows per block, 128 threads per row
    for (int row0 = blockIdx.x * 2; row0 < R; row0 += gridDim.x * 2) {
        int row = row0 + slot;
        bool active = row < R;
        if (active && j < 64)
            vbuf[slot][j] = r_in[(size_t)row * 64 + j];
        __syncthreads();
        if (active && j < 64) {
            float acc = 0.f;
#pragma unroll
            for (int k = 0; k < 64; k++) acc += vbuf[slot][k] * W1s[k * 64 + j];
            acc += b1s[j];
            t1buf[slot][j] = acc >= 0.f ? acc : 0.01f * acc;
        }
        __syncthreads();
        if (active) {
            float acc = 0.f;
#pragma unroll
            for (int k = 0; k < 64; k++) acc += t1buf[slot][k] * Wss[k * 128 + j];
            acc += bss[j];
            feat[(size_t)row * 128 + j] = acc;
            float lk = acc >= 0.f ? acc : 0.2f * acc;
            float p = lk * atts[j];
#pragma unroll
            for (int m = 16; m >= 1; m >>= 1) p += __shfl_xor(p, m, 32);
            if ((j & 31) == 0) score_src[(size_t)row * 4 + (j >> 5)] = p;
        }
        __syncthreads();
    }
}

// ---------------- gather-reduce 1: fused softmax + weighted sum + head-sum ----------------
// one wave per dst node; lane owns floats [lane*2, lane*2+1] of the 128 (head = lane/16)
__global__ __launch_bounds__(256) void k_gather1(
        const float* __restrict__ feat, const float* __restrict__ score,
        const int* __restrict__ src1, const int* __restrict__ eid,
        const unsigned* __restrict__ offs, float* __restrict__ out, int ND, int E1) {
    int wid = (blockIdx.x * blockDim.x + threadIdx.x) >> 6;
    int lane = threadIdx.x & 63;
    if (wid >= ND) return;
    unsigned beg = offs[wid];
    unsigned end = (wid + 1 < ND) ? offs[wid + 1] : (unsigned)E1;
    const float NEG = -3.0e38f;
    float4 mx = {NEG, NEG, NEG, NEG};
    int s_reg = 0;
    float4 sc_reg = {NEG, NEG, NEG, NEG};
    bool single = (end - beg) <= 64u;
    // pass A: per-head max (and cache metadata when segment fits one chunk)
    for (unsigned base = beg; base < end; base += 64u) {
        int m = (int)min(64u, end - base);
        float4 sc = {NEG, NEG, NEG, NEG};
        int s = 0;
        if (lane < m) {
            int e = eid[base + lane];
            s = src1[e];
            sc = ((const float4*)score)[s];
        }
        if (single) { s_reg = s; sc_reg = sc; }
        mx.x = fmaxf(mx.x, sc.x); mx.y = fmaxf(mx.y, sc.y);
        mx.z = fmaxf(mx.z, sc.z); mx.w = fmaxf(mx.w, sc.w);
    }
#pragma unroll
    for (int o = 1; o < 64; o <<= 1) {
        mx.x = fmaxf(mx.x, __shfl_xor(mx.x, o));
        mx.y = fmaxf(mx.y, __shfl_xor(mx.y, o));
        mx.z = fmaxf(mx.z, __shfl_xor(mx.z, o));
        mx.w = fmaxf(mx.w, __shfl_xor(mx.w, o));
    }
    int h = lane >> 4;
    float mh = h == 0 ? mx.x : h == 1 ? mx.y : h == 2 ? mx.z : mx.w;
    float2 acc = {0.f, 0.f};
    float sex = 0.f;
    // pass B: accumulate exp(score-max)*feat in registers
    for (unsigned base = beg; base < end; base += 64u) {
        int m = (int)min(64u, end - base);
        int s;
        float4 sc;
        if (single) {
            s = s_reg; sc = sc_reg;
        } else {
            s = 0; sc.x = sc.y = sc.z = sc.w = 0.f;
            if (lane < m) {
                int e = eid[base + lane];
                s = src1[e];
                sc = ((const float4*)score)[s];
            }
        }
        for (int j = 0; j < m; j++) {
            int sj = __shfl(s, j);
            float sx = __shfl(sc.x, j), sy = __shfl(sc.y, j);
            float sz = __shfl(sc.z, j), sw = __shfl(sc.w, j);
            float scj = h == 0 ? sx : h == 1 ? sy : h == 2 ? sz : sw;
            float ex = __expf(scj - mh);
            float2 v = ((const float2*)(feat + (size_t)sj * 128))[lane];
            acc.x += v.x * ex;
            acc.y += v.y * ex;
            sex += ex;
        }
    }
    float inv = 1.f / sex;
    acc.x *= inv; acc.y *= inv;
    // sum across the 4 heads: lanes {l, l+16, l+32, l+48} hold the same output pair
    acc.x += __shfl_xor(acc.x, 16); acc.x += __shfl_xor(acc.x, 32);
    acc.y += __shfl_xor(acc.y, 16); acc.y += __shfl_xor(acc.y, 32);
    if (lane < 16) ((float2*)(out + (size_t)wid * 32))[lane] = acc;
}

extern "C" void kernel_launch(void* const* d_in, const int* in_sizes, int n_in,
                              void* d_out, int out_size, void* d_ws, size_t ws_size,
                              hipStream_t stream) {
    const float* x      = (const float*)d_in[0];
    const float* norm_n = (const float*)d_in[1];
    const float* norm_e = (const float*)d_in[2];
    const float* W1     = (const float*)d_in[3];
    const float* b1     = (const float*)d_in[4];
    const float* Wsrc   = (const float*)d_in[5];
    const float* bsrc   = (const float*)d_in[6];
    const float* attn   = (const float*)d_in[7];
    const int* src0     = (const int*)d_in[8];
    const int* dst0     = (const int*)d_in[9];
    const int* node_graph = (const int*)d_in[10];
    const int* src1     = (const int*)d_in[11];
    const int* dst1     = (const int*)d_in[12];
    float* out = (float*)d_out;

    char* ws = (char*)d_ws;
    size_t off = 0;
    auto alloc = [&](size_t elems) { void* p = ws + off; off += elems * 4; return p; };

    // zero-init region (histogram counters) first
    unsigned* cnt0 = (unsigned*)alloc(Rc);      // edges per review-graph
    unsigned* cnt1 = (unsigned*)alloc(NDc);     // edges per dst node
    unsigned* cntN = (unsigned*)alloc(Rc);      // nodes per review-graph
    size_t zero_bytes = off;
    unsigned* offs0   = (unsigned*)alloc(Rc);
    unsigned* cursor0 = (unsigned*)alloc(Rc);
    unsigned* offs1   = (unsigned*)alloc(NDc);
    unsigned* cursor1 = (unsigned*)alloc(NDc);
    unsigned* bsum    = (unsigned*)alloc(1024);
    int* eid0 = (int*)alloc(E0c);
    int* eid1 = (int*)alloc(E1c);
    float* r_mean    = (float*)alloc((size_t)Rc * 64);
    float* feat      = (float*)alloc((size_t)Rc * 128);
    float* score_src = (float*)alloc((size_t)Rc * 4);

    hipMemsetAsync(d_ws, 0, zero_bytes, stream);

    // histograms + node counts
    k_count<<<(N0c + 255) / 256, 256, 0, stream>>>(node_graph, cntN, N0c);
    k_hist0<<<(E0c + 255) / 256, 256, 0, stream>>>(dst0, node_graph, cnt0, E0c);
    k_hist1<<<(E1c + 255) / 256, 256, 0, stream>>>(dst1, cnt1, E1c);

    // CSR scan graph0 (R bins)
    int nb0 = (Rc + 1023) / 1024;
    k_scan1<<<nb0, 1024, 0, stream>>>(cnt0, offs0, bsum, Rc);
    k_scan2<<<1, 1024, 0, stream>>>(bsum, nb0);
    k_scan3<<<nb0, 1024, 0, stream>>>(offs0, bsum, cursor0, Rc);
    // CSR scan graph1 (ND bins) — bsum reused (stream-ordered)
    int nb1 = (NDc + 1023) / 1024;
    k_scan1<<<nb1, 1024, 0, stream>>>(cnt1, offs1, bsum, NDc);
    k_scan2<<<1, 1024, 0, stream>>>(bsum, nb1);
    k_scan3<<<nb1, 1024, 0, stream>>>(offs1, bsum, cursor1, NDc);

    // place edges
    k_place0<<<(E0c + 255) / 256, 256, 0, stream>>>(dst0, node_graph, cursor0, eid0, E0c);
    k_place1<<<(E1c + 255) / 256, 256, 0, stream>>>(dst1, cursor1, eid1, E1c);

    // gather-reduce stages
    k_gather0<<<((size_t)Rc * 64 + 255) / 256, 256, 0, stream>>>(
        x, norm_n, norm_e, src0, dst0, eid0, offs0, cntN, r_mean, Rc, E0c);
    k_mlp<<<2048, 256, 0, stream>>>(r_mean, W1, b1, Wsrc, bsrc, attn, feat, score_src, Rc);
    k_gather1<<<((size_t)NDc * 64 + 255) / 256, 256, 0, stream>>>(
        feat, score_src, src1, eid1, offs1, out, NDc, E1c);
}

// Round 4
// 825.972 us; speedup vs baseline: 4.7659x; 1.1979x over previous
//
#include <hip/hip_runtime.h>
#include <math.h>

#define N0c 500000
#define Rc  100000
#define NDc 50000
#define E0c 2000000
#define E1c 1000000
#define NBINS (Rc + NDc)

// ---------------- fused histograms: cnt[0..Rc)=edges0 per graph, cnt[Rc..)=edges1 per dst,
//                  cntN = nodes per graph ----------------
__global__ void k_hist_all(const int* __restrict__ dst0, const int* __restrict__ node_graph,
                           const int* __restrict__ dst1, unsigned* __restrict__ cnt,
                           unsigned* __restrict__ cntN, int E0, int E1, int N0) {
    int i = blockIdx.x * blockDim.x + threadIdx.x;
    if (i < E0) atomicAdd(&cnt[node_graph[dst0[i]]], 1u);
    if (i < E1) atomicAdd(&cnt[Rc + dst1[i]], 1u);
    if (i < N0) atomicAdd(&cntN[node_graph[i]], 1u);
}

// ---------------- 3-pass exclusive scan over NBINS ----------------
__global__ void k_scan1(const unsigned* __restrict__ in, unsigned* __restrict__ out,
                        unsigned* __restrict__ bsum, int n) {
    __shared__ unsigned s[1024];
    int i = blockIdx.x * 1024 + threadIdx.x;
    unsigned v = (i < n) ? in[i] : 0u;
    s[threadIdx.x] = v;
    __syncthreads();
    for (int off = 1; off < 1024; off <<= 1) {
        unsigned t = (threadIdx.x >= off) ? s[threadIdx.x - off] : 0u;
        __syncthreads();
        s[threadIdx.x] += t;
        __syncthreads();
    }
    if (i < n) out[i] = s[threadIdx.x] - v;  // exclusive within block
    if (threadIdx.x == 1023) bsum[blockIdx.x] = s[1023];
}

__global__ void k_scan2(unsigned* __restrict__ bsum, int nb) {
    __shared__ unsigned s[1024];
    unsigned v = (threadIdx.x < nb) ? bsum[threadIdx.x] : 0u;
    s[threadIdx.x] = v;
    __syncthreads();
    for (int off = 1; off < 1024; off <<= 1) {
        unsigned t = (threadIdx.x >= off) ? s[threadIdx.x - off] : 0u;
        __syncthreads();
        s[threadIdx.x] += t;
        __syncthreads();
    }
    if (threadIdx.x < nb) bsum[threadIdx.x] = s[threadIdx.x] - v;  // exclusive
}

__global__ void k_scan3(unsigned* __restrict__ out, const unsigned* __restrict__ bsum,
                        unsigned* __restrict__ cursor, int n) {
    int i = blockIdx.x * 1024 + threadIdx.x;
    if (i < n) {
        unsigned v = out[i] + bsum[blockIdx.x];
        out[i] = v;
        cursor[i] = v;
    }
}

// ---------------- fused place: write sorted payloads (no eid indirection) ----------------
__global__ void k_place_all(const int* __restrict__ src0, const int* __restrict__ dst0,
                            const int* __restrict__ node_graph,
                            const float* __restrict__ norm_n, const float* __restrict__ norm_e,
                            const int* __restrict__ src1, const int* __restrict__ dst1,
                            unsigned* __restrict__ cursor, int2* __restrict__ sorted0,
                            int* __restrict__ sorted1, int E0, int E1) {
    int i = blockIdx.x * blockDim.x + threadIdx.x;
    if (i < E0) {
        int s = src0[i], d = dst0[i];
        float coef = norm_n[s] * norm_n[d] * norm_e[i];
        unsigned p = atomicAdd(&cursor[node_graph[d]], 1u);
        sorted0[p] = make_int2(s, __float_as_int(coef));
    }
    if (i < E1) {
        unsigned p = atomicAdd(&cursor[Rc + dst1[i]], 1u) - (unsigned)E0c;
        sorted1[p] = src1[i];
    }
}

// ---------------- gather-reduce 0: one wave per graph, 4 edges in flight ----------------
// lane = (q<<4)|l : group q handles edge slots 4t+q, lane loads x row as float4[l]
__global__ __launch_bounds__(256) void k_gather0(
        const float* __restrict__ x, const int2* __restrict__ sorted0,
        const unsigned* __restrict__ offs, const unsigned* __restrict__ cntN,
        float* __restrict__ r, int R) {
    int wid = (blockIdx.x * blockDim.x + threadIdx.x) >> 6;
    int lane = threadIdx.x & 63;
    if (wid >= R) return;
    unsigned beg = offs[wid], end = offs[wid + 1];  // offs[Rc] == E0c (start of set-1 bins)
    int q = lane >> 4, l = lane & 15;
    float4 acc = {0.f, 0.f, 0.f, 0.f};
    for (unsigned base = beg; base < end; base += 64u) {
        int m = (int)min(64u, end - base);
        int s = 0;
        float c = 0.f;
        if (lane < m) {
            int2 p = sorted0[base + lane];
            s = p.x;
            c = __int_as_float(p.y);
        }
        int rounds = (m + 3) >> 2;
        for (int t = 0; t < rounds; t++) {
            int idx = 4 * t + q;            // idx >= m broadcasts (s=0,c=0) -> contributes 0
            int sj = __shfl(s, idx);
            float cj = __shfl(c, idx);
            float4 v = ((const float4*)(x + (size_t)sj * 64))[l];
            acc.x += v.x * cj; acc.y += v.y * cj;
            acc.z += v.z * cj; acc.w += v.w * cj;
        }
    }
    // sum the 4 groups' partials (lanes with equal l hold the same feature quad)
    acc.x += __shfl_xor(acc.x, 16); acc.y += __shfl_xor(acc.y, 16);
    acc.z += __shfl_xor(acc.z, 16); acc.w += __shfl_xor(acc.w, 16);
    acc.x += __shfl_xor(acc.x, 32); acc.y += __shfl_xor(acc.y, 32);
    acc.z += __shfl_xor(acc.z, 32); acc.w += __shfl_xor(acc.w, 32);
    if (q == 0) {
        float inv = 1.f / (float)cntN[wid];
        float4 o = {acc.x * inv, acc.y * inv, acc.z * inv, acc.w * inv};
        ((float4*)(r + (size_t)wid * 64))[l] = o;
    }
}

// ---------------- fused MLP + GATv2 source score ----------------
__global__ __launch_bounds__(256) void k_mlp(const float* __restrict__ r_in,
                                             const float* __restrict__ W1,
                                             const float* __restrict__ b1,
                                             const float* __restrict__ Wsrc,
                                             const float* __restrict__ bsrc,
                                             const float* __restrict__ attn,
                                             float* __restrict__ feat,
                                             float* __restrict__ score_src, int R) {
    __shared__ float W1s[64 * 64];
    __shared__ float Wss[64 * 128];
    __shared__ float b1s[64], bss[128], atts[128];
    __shared__ float vbuf[2][64], t1buf[2][64];
    int tid = threadIdx.x;
    for (int i = tid; i < 4096; i += 256) W1s[i] = W1[i];
    for (int i = tid; i < 8192; i += 256) Wss[i] = Wsrc[i];
    if (tid < 64) b1s[tid] = b1[tid];
    if (tid < 128) bss[tid] = bsrc[tid];
    if (tid < 128) atts[tid] = attn[tid];
    __syncthreads();

    int slot = tid >> 7, j = tid & 127;  // 2 rows per block
    for (int row0 = blockIdx.x * 2; row0 < R; row0 += gridDim.x * 2) {
        int row = row0 + slot;
        bool active = row < R;
        if (active && j < 64)
            vbuf[slot][j] = r_in[(size_t)row * 64 + j];
        __syncthreads();
        if (active && j < 64) {
            float acc = 0.f;
#pragma unroll
            for (int k = 0; k < 64; k++) acc += vbuf[slot][k] * W1s[k * 64 + j];
            acc += b1s[j];
            t1buf[slot][j] = acc >= 0.f ? acc : 0.01f * acc;
        }
        __syncthreads();
        if (active) {
            float acc = 0.f;
#pragma unroll
            for (int k = 0; k < 64; k++) acc += t1buf[slot][k] * Wss[k * 128 + j];
            acc += bss[j];
            feat[(size_t)row * 128 + j] = acc;
            float lk = acc >= 0.f ? acc : 0.2f * acc;
            float p = lk * atts[j];
#pragma unroll
            for (int m = 16; m >= 1; m >>= 1) p += __shfl_xor(p, m, 32);
            if ((j & 31) == 0) score_src[(size_t)row * 4 + (j >> 5)] = p;
        }
        __syncthreads();
    }
}

// ---------------- gather-reduce 1: one wave per dst node, 2 edges in flight ----------------
// lane = (q<<5)|l : group q handles edge slots 2t+q; lane covers feat floats [4l,4l+4), head=l/8
__global__ __launch_bounds__(256) void k_gather1(
        const float* __restrict__ feat, const float* __restrict__ score,
        const int* __restrict__ sorted1, const unsigned* __restrict__ offs1,
        float* __restrict__ out, int ND) {
    int wid = (blockIdx.x * blockDim.x + threadIdx.x) >> 6;
    int lane = threadIdx.x & 63;
    if (wid >= ND) return;
    unsigned beg = offs1[wid] - (unsigned)E0c;
    unsigned end = (wid + 1 < ND) ? offs1[wid + 1] - (unsigned)E0c : (unsigned)E1c;
    int q = lane >> 5, l = lane & 31, h = l >> 3;
    const float NEG = -3.0e38f;
    float4 mx = {NEG, NEG, NEG, NEG};
    int s_reg = 0;
    float4 sc_reg = {NEG, NEG, NEG, NEG};
    bool single = (end - beg) <= 64u;
    // pass A: per-head max (cache src/score when the segment fits one chunk)
    for (unsigned base = beg; base < end; base += 64u) {
        int m = (int)min(64u, end - base);
        int s = 0;
        float4 sc = {NEG, NEG, NEG, NEG};
        if (lane < m) {
            s = sorted1[base + lane];
            sc = ((const float4*)score)[s];
        }
        if (single) { s_reg = s; sc_reg = sc; }
        mx.x = fmaxf(mx.x, sc.x); mx.y = fmaxf(mx.y, sc.y);
        mx.z = fmaxf(mx.z, sc.z); mx.w = fmaxf(mx.w, sc.w);
    }
#pragma unroll
    for (int o = 1; o < 64; o <<= 1) {
        mx.x = fmaxf(mx.x, __shfl_xor(mx.x, o));
        mx.y = fmaxf(mx.y, __shfl_xor(mx.y, o));
        mx.z = fmaxf(mx.z, __shfl_xor(mx.z, o));
        mx.w = fmaxf(mx.w, __shfl_xor(mx.w, o));
    }
    float mh = h == 0 ? mx.x : h == 1 ? mx.y : h == 2 ? mx.z : mx.w;
    float4 acc = {0.f, 0.f, 0.f, 0.f};
    float sex = 0.f;
    // pass B: acc += exp(score-max) * feat, 2 edges per round
    for (unsigned base = beg; base < end; base += 64u) {
        int m = (int)min(64u, end - base);
        int s;
        float4 sc;
        if (single) {
            s = s_reg; sc = sc_reg;
        } else {
            s = 0; sc.x = sc.y = sc.z = sc.w = NEG;
            if (lane < m) {
                s = sorted1[base + lane];
                sc = ((const float4*)score)[s];
            }
        }
        int rounds = (m + 1) >> 1;
        for (int t = 0; t < rounds; t++) {
            int idx = 2 * t + q;            // idx >= m broadcasts score NEG -> ex = 0
            int sj = __shfl(s, idx);
            float sx = __shfl(sc.x, idx), sy = __shfl(sc.y, idx);
            float sz = __shfl(sc.z, idx), sw = __shfl(sc.w, idx);
            float sch = h == 0 ? sx : h == 1 ? sy : h == 2 ? sz : sw;
            float ex = __expf(sch - mh);
            float4 v = ((const float4*)(feat + (size_t)sj * 128))[l];
            acc.x += v.x * ex; acc.y += v.y * ex;
            acc.z += v.z * ex; acc.w += v.w * ex;
            sex += ex;
        }
    }
    // combine the two groups
    acc.x += __shfl_xor(acc.x, 32); acc.y += __shfl_xor(acc.y, 32);
    acc.z += __shfl_xor(acc.z, 32); acc.w += __shfl_xor(acc.w, 32);
    sex += __shfl_xor(sex, 32);
    float inv = 1.f / sex;
    acc.x *= inv; acc.y *= inv; acc.z *= inv; acc.w *= inv;
    // sum across the 4 heads: lanes with equal (l mod 8) hold same out dims, heads 0..3
    acc.x += __shfl_xor(acc.x, 8);  acc.y += __shfl_xor(acc.y, 8);
    acc.z += __shfl_xor(acc.z, 8);  acc.w += __shfl_xor(acc.w, 8);
    acc.x += __shfl_xor(acc.x, 16); acc.y += __shfl_xor(acc.y, 16);
    acc.z += __shfl_xor(acc.z, 16); acc.w += __shfl_xor(acc.w, 16);
    if (lane < 8) ((float4*)(out + (size_t)wid * 32))[lane] = acc;
}

extern "C" void kernel_launch(void* const* d_in, const int* in_sizes, int n_in,
                              void* d_out, int out_size, void* d_ws, size_t ws_size,
                              hipStream_t stream) {
    const float* x      = (const float*)d_in[0];
    const float* norm_n = (const float*)d_in[1];
    const float* norm_e = (const float*)d_in[2];
    const float* W1     = (const float*)d_in[3];
    const float* b1     = (const float*)d_in[4];
    const float* Wsrc   = (const float*)d_in[5];
    const float* bsrc   = (const float*)d_in[6];
    const float* attn   = (const float*)d_in[7];
    const int* src0     = (const int*)d_in[8];
    const int* dst0     = (const int*)d_in[9];
    const int* node_graph = (const int*)d_in[10];
    const int* src1     = (const int*)d_in[11];
    const int* dst1     = (const int*)d_in[12];
    float* out = (float*)d_out;

    char* ws = (char*)d_ws;
    size_t off = 0;
    auto alloc = [&](size_t elems) { void* p = ws + off; off += elems * 4; return p; };

    unsigned* cnt  = (unsigned*)alloc(NBINS);    // zeroed
    unsigned* cntN = (unsigned*)alloc(Rc);       // zeroed
    size_t zero_bytes = off;
    unsigned* offs    = (unsigned*)alloc(NBINS);
    unsigned* cursor  = (unsigned*)alloc(NBINS);
    unsigned* bsum    = (unsigned*)alloc(1024);
    int2* sorted0     = (int2*)alloc((size_t)E0c * 2);
    int* sorted1      = (int*)alloc(E1c);
    float* r_mean     = (float*)alloc((size_t)Rc * 64);
    float* feat       = (float*)alloc((size_t)Rc * 128);
    float* score_src  = (float*)alloc((size_t)Rc * 4);

    hipMemsetAsync(d_ws, 0, zero_bytes, stream);

    k_hist_all<<<(E0c + 255) / 256, 256, 0, stream>>>(dst0, node_graph, dst1, cnt, cntN,
                                                      E0c, E1c, N0c);
    int nb = (NBINS + 1023) / 1024;
    k_scan1<<<nb, 1024, 0, stream>>>(cnt, offs, bsum, NBINS);
    k_scan2<<<1, 1024, 0, stream>>>(bsum, nb);
    k_scan3<<<nb, 1024, 0, stream>>>(offs, bsum, cursor, NBINS);

    k_place_all<<<(E0c + 255) / 256, 256, 0, stream>>>(src0, dst0, node_graph, norm_n, norm_e,
                                                       src1, dst1, cursor, sorted0, sorted1,
                                                       E0c, E1c);

    k_gather0<<<((size_t)Rc * 64 + 255) / 256, 256, 0, stream>>>(
        x, sorted0, offs, cntN, r_mean, Rc);
    k_mlp<<<2048, 256, 0, stream>>>(r_mean, W1, b1, Wsrc, bsrc, attn, feat, score_src, Rc);
    k_gather1<<<((size_t)NDc * 64 + 255) / 256, 256, 0, stream>>>(
        feat, score_src, sorted1, offs + Rc, out, NDc);
}

// Round 5
// 750.610 us; speedup vs baseline: 5.2444x; 1.1004x over previous
//
#include <hip/hip_runtime.h>
#include <math.h>

#define N0c 500000
#define Rc  100000
#define NDc 50000
#define E0c 2000000
#define E1c 1000000
#define NBINS (Rc + NDc)
#define MTILE 32   // rows per k_mlp block; 100000 % 32 == 0 ? no: 100000/32 = 3125 exactly

// ---------------- fused histograms ----------------
__global__ void k_hist_all(const int* __restrict__ dst0, const int* __restrict__ node_graph,
                           const int* __restrict__ dst1, unsigned* __restrict__ cnt,
                           unsigned* __restrict__ cntN, int E0, int E1, int N0) {
    int i = blockIdx.x * blockDim.x + threadIdx.x;
    if (i < E0) atomicAdd(&cnt[node_graph[dst0[i]]], 1u);
    if (i < E1) atomicAdd(&cnt[Rc + dst1[i]], 1u);
    if (i < N0) atomicAdd(&cntN[node_graph[i]], 1u);
}

// ---------------- 3-pass exclusive scan over NBINS ----------------
__global__ void k_scan1(const unsigned* __restrict__ in, unsigned* __restrict__ out,
                        unsigned* __restrict__ bsum, int n) {
    __shared__ unsigned s[1024];
    int i = blockIdx.x * 1024 + threadIdx.x;
    unsigned v = (i < n) ? in[i] : 0u;
    s[threadIdx.x] = v;
    __syncthreads();
    for (int off = 1; off < 1024; off <<= 1) {
        unsigned t = (threadIdx.x >= off) ? s[threadIdx.x - off] : 0u;
        __syncthreads();
        s[threadIdx.x] += t;
        __syncthreads();
    }
    if (i < n) out[i] = s[threadIdx.x] - v;
    if (threadIdx.x == 1023) bsum[blockIdx.x] = s[1023];
}

__global__ void k_scan2(unsigned* __restrict__ bsum, int nb) {
    __shared__ unsigned s[1024];
    unsigned v = (threadIdx.x < nb) ? bsum[threadIdx.x] : 0u;
    s[threadIdx.x] = v;
    __syncthreads();
    for (int off = 1; off < 1024; off <<= 1) {
        unsigned t = (threadIdx.x >= off) ? s[threadIdx.x - off] : 0u;
        __syncthreads();
        s[threadIdx.x] += t;
        __syncthreads();
    }
    if (threadIdx.x < nb) bsum[threadIdx.x] = s[threadIdx.x] - v;
}

__global__ void k_scan3(unsigned* __restrict__ out, const unsigned* __restrict__ bsum,
                        unsigned* __restrict__ cursor, int n) {
    int i = blockIdx.x * 1024 + threadIdx.x;
    if (i < n) {
        unsigned v = out[i] + bsum[blockIdx.x];
        out[i] = v;
        cursor[i] = v;
    }
}

// ---------------- fused place: write sorted payloads ----------------
__global__ void k_place_all(const int* __restrict__ src0, const int* __restrict__ dst0,
                            const int* __restrict__ node_graph,
                            const float* __restrict__ norm_n, const float* __restrict__ norm_e,
                            const int* __restrict__ src1, const int* __restrict__ dst1,
                            unsigned* __restrict__ cursor, int2* __restrict__ sorted0,
                            int* __restrict__ sorted1, int E0, int E1) {
    int i = blockIdx.x * blockDim.x + threadIdx.x;
    if (i < E0) {
        int s = src0[i], d = dst0[i];
        float coef = norm_n[s] * norm_n[d] * norm_e[i];
        unsigned p = atomicAdd(&cursor[node_graph[d]], 1u);
        sorted0[p] = make_int2(s, __float_as_int(coef));
    }
    if (i < E1) {
        unsigned p = atomicAdd(&cursor[Rc + dst1[i]], 1u) - (unsigned)E0c;
        sorted1[p] = src1[i];
    }
}

// ---------------- gather-reduce 0 (unchanged from R4) ----------------
__global__ __launch_bounds__(256) void k_gather0(
        const float* __restrict__ x, const int2* __restrict__ sorted0,
        const unsigned* __restrict__ offs, const unsigned* __restrict__ cntN,
        float* __restrict__ r, int R) {
    int wid = (blockIdx.x * blockDim.x + threadIdx.x) >> 6;
    int lane = threadIdx.x & 63;
    if (wid >= R) return;
    unsigned beg = offs[wid], end = offs[wid + 1];
    int q = lane >> 4, l = lane & 15;
    float4 acc = {0.f, 0.f, 0.f, 0.f};
    for (unsigned base = beg; base < end; base += 64u) {
        int m = (int)min(64u, end - base);
        int s = 0;
        float c = 0.f;
        if (lane < m) {
            int2 p = sorted0[base + lane];
            s = p.x;
            c = __int_as_float(p.y);
        }
        int rounds = (m + 3) >> 2;
        for (int t = 0; t < rounds; t++) {
            int idx = 4 * t + q;
            int sj = __shfl(s, idx);
            float cj = __shfl(c, idx);
            float4 v = ((const float4*)(x + (size_t)sj * 64))[l];
            acc.x += v.x * cj; acc.y += v.y * cj;
            acc.z += v.z * cj; acc.w += v.w * cj;
        }
    }
    acc.x += __shfl_xor(acc.x, 16); acc.y += __shfl_xor(acc.y, 16);
    acc.z += __shfl_xor(acc.z, 16); acc.w += __shfl_xor(acc.w, 16);
    acc.x += __shfl_xor(acc.x, 32); acc.y += __shfl_xor(acc.y, 32);
    acc.z += __shfl_xor(acc.z, 32); acc.w += __shfl_xor(acc.w, 32);
    if (q == 0) {
        float inv = 1.f / (float)cntN[wid];
        float4 o = {acc.x * inv, acc.y * inv, acc.z * inv, acc.w * inv};
        ((float4*)(r + (size_t)wid * 64))[l] = o;
    }
}

// ---------------- register-blocked MLP: 32 rows/block, 512 threads, 3 syncs ----------------
// thread: row = tid>>4 (0..31), colgrp c = tid&15. GEMM1: 4 outputs (cols 4c..4c+3).
// GEMM2: 8 outputs (cols 8c..8c+7). Input rows in LDS stride-68 (conflict-free broadcast).
__global__ __launch_bounds__(512) void k_mlp(const float* __restrict__ r_in,
                                             const float* __restrict__ W1,
                                             const float* __restrict__ b1,
                                             const float* __restrict__ Wsrc,
                                             const float* __restrict__ bsrc,
                                             const float* __restrict__ attn,
                                             float* __restrict__ feat,
                                             float* __restrict__ score_src, int R) {
    __shared__ float W1s[64 * 64];    // [k][j]
    __shared__ float Wss[64 * 128];   // [k][j]
    __shared__ float b1s[64], bss[128], atts[128];
    __shared__ float in_s[MTILE * 68];
    __shared__ float t1_s[MTILE * 68];
    int tid = threadIdx.x;
    for (int i = tid; i < 4096; i += 512) W1s[i] = W1[i];
    for (int i = tid; i < 8192; i += 512) Wss[i] = Wsrc[i];
    if (tid < 64) b1s[tid] = b1[tid];
    if (tid >= 64 && tid < 192) bss[tid - 64] = bsrc[tid - 64];
    if (tid >= 192 && tid < 320) atts[tid - 192] = attn[tid - 192];

    int row = tid >> 4, c = tid & 15;
    size_t grow = (size_t)blockIdx.x * MTILE + row;   // grid = R/MTILE exactly
    // stage 32 input rows (coalesced float4)
    float4 vin = ((const float4*)(r_in + grow * 64))[c];
    *((float4*)&in_s[row * 68 + c * 4]) = vin;
    __syncthreads();

    // ---- GEMM1: t1 = leaky(in @ W1 + b1, 0.01) ----
    {
        float4 a = {0.f, 0.f, 0.f, 0.f};
        const float* wcol = W1s + c * 4;
        const float* inr = in_s + row * 68;
#pragma unroll
        for (int k = 0; k < 64; k++) {
            float iv = inr[k];
            float4 w = *((const float4*)(wcol + k * 64));
            a.x += iv * w.x; a.y += iv * w.y;
            a.z += iv * w.z; a.w += iv * w.w;
        }
        const float4 bb = *((const float4*)(b1s + c * 4));
        a.x += bb.x; a.y += bb.y; a.z += bb.z; a.w += bb.w;
        a.x = a.x >= 0.f ? a.x : 0.01f * a.x;
        a.y = a.y >= 0.f ? a.y : 0.01f * a.y;
        a.z = a.z >= 0.f ? a.z : 0.01f * a.z;
        a.w = a.w >= 0.f ? a.w : 0.01f * a.w;
        *((float4*)&t1_s[row * 68 + c * 4]) = a;
    }
    __syncthreads();

    // ---- GEMM2: feat = t1 @ Wsrc + bsrc; score = sum leaky(feat,0.2)*attn per head ----
    {
        float4 a0 = {0.f, 0.f, 0.f, 0.f}, a1 = {0.f, 0.f, 0.f, 0.f};
        const float* w2 = Wss + c * 8;
        const float* t1r = t1_s + row * 68;
#pragma unroll
        for (int k = 0; k < 64; k++) {
            float tv = t1r[k];
            float4 w0 = *((const float4*)(w2 + k * 128));
            float4 w1 = *((const float4*)(w2 + k * 128 + 4));
            a0.x += tv * w0.x; a0.y += tv * w0.y;
            a0.z += tv * w0.z; a0.w += tv * w0.w;
            a1.x += tv * w1.x; a1.y += tv * w1.y;
            a1.z += tv * w1.z; a1.w += tv * w1.w;
        }
        const float4 b0 = *((const float4*)(bss + c * 8));
        const float4 b1v = *((const float4*)(bss + c * 8 + 4));
        a0.x += b0.x; a0.y += b0.y; a0.z += b0.z; a0.w += b0.w;
        a1.x += b1v.x; a1.y += b1v.y; a1.z += b1v.z; a1.w += b1v.w;
        float4* fp = (float4*)(feat + grow * 128 + c * 8);
        fp[0] = a0; fp[1] = a1;
        const float4 at0 = *((const float4*)(atts + c * 8));
        const float4 at1 = *((const float4*)(atts + c * 8 + 4));
        float p =
            (a0.x >= 0.f ? a0.x : 0.2f * a0.x) * at0.x +
            (a0.y >= 0.f ? a0.y : 0.2f * a0.y) * at0.y +
            (a0.z >= 0.f ? a0.z : 0.2f * a0.z) * at0.z +
            (a0.w >= 0.f ? a0.w : 0.2f * a0.w) * at0.w +
            (a1.x >= 0.f ? a1.x : 0.2f * a1.x) * at1.x +
            (a1.y >= 0.f ? a1.y : 0.2f * a1.y) * at1.y +
            (a1.z >= 0.f ? a1.z : 0.2f * a1.z) * at1.z +
            (a1.w >= 0.f ? a1.w : 0.2f * a1.w) * at1.w;
        // lanes 4h..4h+3 (same row, head h=c>>2) hold partials
        p += __shfl_xor(p, 1);
        p += __shfl_xor(p, 2);
        if ((c & 3) == 0) score_src[grow * 4 + (c >> 2)] = p;
    }
}

// ---------------- gather-reduce 1 (unchanged from R4) ----------------
__global__ __launch_bounds__(256) void k_gather1(
        const float* __restrict__ feat, const float* __restrict__ score,
        const int* __restrict__ sorted1, const unsigned* __restrict__ offs1,
        float* __restrict__ out, int ND) {
    int wid = (blockIdx.x * blockDim.x + threadIdx.x) >> 6;
    int lane = threadIdx.x & 63;
    if (wid >= ND) return;
    unsigned beg = offs1[wid] - (unsigned)E0c;
    unsigned end = (wid + 1 < ND) ? offs1[wid + 1] - (unsigned)E0c : (unsigned)E1c;
    int q = lane >> 5, l = lane & 31, h = l >> 3;
    const float NEG = -3.0e38f;
    float4 mx = {NEG, NEG, NEG, NEG};
    int s_reg = 0;
    float4 sc_reg = {NEG, NEG, NEG, NEG};
    bool single = (end - beg) <= 64u;
    for (unsigned base = beg; base < end; base += 64u) {
        int m = (int)min(64u, end - base);
        int s = 0;
        float4 sc = {NEG, NEG, NEG, NEG};
        if (lane < m) {
            s = sorted1[base + lane];
            sc = ((const float4*)score)[s];
        }
        if (single) { s_reg = s; sc_reg = sc; }
        mx.x = fmaxf(mx.x, sc.x); mx.y = fmaxf(mx.y, sc.y);
        mx.z = fmaxf(mx.z, sc.z); mx.w = fmaxf(mx.w, sc.w);
    }
#pragma unroll
    for (int o = 1; o < 64; o <<= 1) {
        mx.x = fmaxf(mx.x, __shfl_xor(mx.x, o));
        mx.y = fmaxf(mx.y, __shfl_xor(mx.y, o));
        mx.z = fmaxf(mx.z, __shfl_xor(mx.z, o));
        mx.w = fmaxf(mx.w, __shfl_xor(mx.w, o));
    }
    float mh = h == 0 ? mx.x : h == 1 ? mx.y : h == 2 ? mx.z : mx.w;
    float4 acc = {0.f, 0.f, 0.f, 0.f};
    float sex = 0.f;
    for (unsigned base = beg; base < end; base += 64u) {
        int m = (int)min(64u, end - base);
        int s;
        float4 sc;
        if (single) {
            s = s_reg; sc = sc_reg;
        } else {
            s = 0; sc.x = sc.y = sc.z = sc.w = NEG;
            if (lane < m) {
                s = sorted1[base + lane];
                sc = ((const float4*)score)[s];
            }
        }
        int rounds = (m + 1) >> 1;
        for (int t = 0; t < rounds; t++) {
            int idx = 2 * t + q;
            int sj = __shfl(s, idx);
            float sx = __shfl(sc.x, idx), sy = __shfl(sc.y, idx);
            float sz = __shfl(sc.z, idx), sw = __shfl(sc.w, idx);
            float sch = h == 0 ? sx : h == 1 ? sy : h == 2 ? sz : sw;
            float ex = __expf(sch - mh);
            float4 v = ((const float4*)(feat + (size_t)sj * 128))[l];
            acc.x += v.x * ex; acc.y += v.y * ex;
            acc.z += v.z * ex; acc.w += v.w * ex;
            sex += ex;
        }
    }
    acc.x += __shfl_xor(acc.x, 32); acc.y += __shfl_xor(acc.y, 32);
    acc.z += __shfl_xor(acc.z, 32); acc.w += __shfl_xor(acc.w, 32);
    sex += __shfl_xor(sex, 32);
    float inv = 1.f / sex;
    acc.x *= inv; acc.y *= inv; acc.z *= inv; acc.w *= inv;
    acc.x += __shfl_xor(acc.x, 8);  acc.y += __shfl_xor(acc.y, 8);
    acc.z += __shfl_xor(acc.z, 8);  acc.w += __shfl_xor(acc.w, 8);
    acc.x += __shfl_xor(acc.x, 16); acc.y += __shfl_xor(acc.y, 16);
    acc.z += __shfl_xor(acc.z, 16); acc.w += __shfl_xor(acc.w, 16);
    if (lane < 8) ((float4*)(out + (size_t)wid * 32))[lane] = acc;
}

extern "C" void kernel_launch(void* const* d_in, const int* in_sizes, int n_in,
                              void* d_out, int out_size, void* d_ws, size_t ws_size,
                              hipStream_t stream) {
    const float* x      = (const float*)d_in[0];
    const float* norm_n = (const float*)d_in[1];
    const float* norm_e = (const float*)d_in[2];
    const float* W1     = (const float*)d_in[3];
    const float* b1     = (const float*)d_in[4];
    const float* Wsrc   = (const float*)d_in[5];
    const float* bsrc   = (const float*)d_in[6];
    const float* attn   = (const float*)d_in[7];
    const int* src0     = (const int*)d_in[8];
    const int* dst0     = (const int*)d_in[9];
    const int* node_graph = (const int*)d_in[10];
    const int* src1     = (const int*)d_in[11];
    const int* dst1     = (const int*)d_in[12];
    float* out = (float*)d_out;

    char* ws = (char*)d_ws;
    size_t off = 0;
    auto alloc = [&](size_t elems) { void* p = ws + off; off += elems * 4; return p; };

    unsigned* cnt  = (unsigned*)alloc(NBINS);    // zeroed
    unsigned* cntN = (unsigned*)alloc(Rc);       // zeroed
    size_t zero_bytes = off;
    unsigned* offs    = (unsigned*)alloc(NBINS);
    unsigned* cursor  = (unsigned*)alloc(NBINS);
    unsigned* bsum    = (unsigned*)alloc(1024);
    int2* sorted0     = (int2*)alloc((size_t)E0c * 2);
    int* sorted1      = (int*)alloc(E1c);
    float* r_mean     = (float*)alloc((size_t)Rc * 64);
    float* feat       = (float*)alloc((size_t)Rc * 128);
    float* score_src  = (float*)alloc((size_t)Rc * 4);

    hipMemsetAsync(d_ws, 0, zero_bytes, stream);

    k_hist_all<<<(E0c + 255) / 256, 256, 0, stream>>>(dst0, node_graph, dst1, cnt, cntN,
                                                      E0c, E1c, N0c);
    int nb = (NBINS + 1023) / 1024;
    k_scan1<<<nb, 1024, 0, stream>>>(cnt, offs, bsum, NBINS);
    k_scan2<<<1, 1024, 0, stream>>>(bsum, nb);
    k_scan3<<<nb, 1024, 0, stream>>>(offs, bsum, cursor, NBINS);

    k_place_all<<<(E0c + 255) / 256, 256, 0, stream>>>(src0, dst0, node_graph, norm_n, norm_e,
                                                       src1, dst1, cursor, sorted0, sorted1,
                                                       E0c, E1c);

    k_gather0<<<((size_t)Rc * 64 + 255) / 256, 256, 0, stream>>>(
        x, sorted0, offs, cntN, r_mean, Rc);
    k_mlp<<<Rc / MTILE, 512, 0, stream>>>(r_mean, W1, b1, Wsrc, bsrc, attn, feat, score_src, Rc);
    k_gather1<<<((size_t)NDc * 64 + 255) / 256, 256, 0, stream>>>(
        feat, score_src, sorted1, offs + Rc, out, NDc);
}